// Round 4
// baseline (514.512 us; speedup 1.0000x reference)
//
#include <hip/hip_runtime.h>
#include <hip/hip_bf16.h>
#include <stdint.h>

typedef __hip_bfloat16 bf16;
typedef __bf16 bf16x8 __attribute__((ext_vector_type(8)));
typedef float f32x4 __attribute__((ext_vector_type(4)));

#define S_LEN 2048
#define EMB   2048
#define NH    16
#define HD    128

// async global->LDS, 16B per lane. LDS dest must be wave-uniform base + lane*16.
__device__ __forceinline__ void glds16(const void* g, void* l) {
  __builtin_amdgcn_global_load_lds(
      (__attribute__((address_space(1))) void*)g,
      (__attribute__((address_space(3))) void*)l,
      16, 0, 0);
}

// ---------------------------------------------------------------------------
// Kernel 0: f32 -> bf16 conversion (4 elements/thread, vectorized)
// ---------------------------------------------------------------------------
__global__ __launch_bounds__(256) void cvt_f32_bf16_k(
    const float* __restrict__ in, bf16* __restrict__ outp)
{
  const int i = blockIdx.x * 256 + threadIdx.x;
  const float4 v = ((const float4*)in)[i];
  bf16 tmp[4];
  tmp[0] = __float2bfloat16(v.x);
  tmp[1] = __float2bfloat16(v.y);
  tmp[2] = __float2bfloat16(v.z);
  tmp[3] = __float2bfloat16(v.w);
  ((uint2*)outp)[i] = *(const uint2*)tmp;
}

// ===========================================================================
// Phased GEMM (m201-style, both GEMMs):
//   tile 128(M) x 256(N), BK=64, 512 threads = 8 waves (2 M x 4 N),
//   per-wave output 64x64, acc[4][4] (64 VGPR).
//   LDS 96KB: A[2buf][2 K-half][128x32] + B[2][2][256x32]. Rows are 64B;
//   swizzle: 16B-chunk index ^= ((row>>1)&3) (inverse-swizzled global src,
//   linear glds dest, swizzled ds_read -> 2 lanes/bank = free).
//   4 phases per K-tile kt (buf b=kt&1, stage target nb=b^1 holds kt+1):
//     P1: stage A-Kh0(kt+1) [1 ld]; read af@Kh0(4) bq01@Kh0(2); 8 MFMA; bar
//     P2: stage B-Kh0(kt+1) [2 ld]; read bq23@Kh0(2); 8 MFMA; vmcnt(3); bar
//     P3: stage A-Kh1(kt+1) [1 ld]; read af@Kh1(4) bq01@Kh1(2); 8 MFMA; bar
//     P4: stage B-Kh1(kt+1) [2 ld]; read bq23@Kh1(2); 8 MFMA; vmcnt(3); bar
//   vmcnt ledger (per wave, 3 loads per K-half-pair): entering P1 = 3 in
//   flight (Kh1(kt)); P2-end vmcnt(3) drains exactly Kh1(kt) (needed P3);
//   P4-end vmcnt(3) drains exactly Kh0(kt+1) (needed next P1). Counted
//   wait + s_barrier collectivizes per-wave guarantees. Tail kt=31: no
//   stages, vmcnt(0). Buffer nb's old content (kt-1) died at prev iter's
//   last barrier -> no write race. Grids: qkv (24,32)=768 = 3 exact
//   rounds/CU (balanced); out (8,32)=256 = 1 round.
// ===========================================================================

// ---------------------------------------------------------------------------
// Kernel 1: qkv = x @ w_qkv^T + b_qkv. Q,K scattered into [b,h,s,d];
// V written TRANSPOSED into v_t [b,h,d,s].
// ---------------------------------------------------------------------------
__global__ __launch_bounds__(512, 2) void gemm_qkv_k(
    const bf16* __restrict__ x, const bf16* __restrict__ wq,
    const float* __restrict__ bias,
    bf16* __restrict__ q_ws, bf16* __restrict__ k_ws, bf16* __restrict__ v_t)
{
  __shared__ alignas(16) bf16 sA[2][2][128 * 32];
  __shared__ alignas(16) bf16 sB[2][2][256 * 32];

  const int t    = threadIdx.x;
  const int lane = t & 63, quad = lane >> 4, l15 = lane & 15;
  const int w    = t >> 6, wm = w >> 2, wn = w & 3;

  const int n0 = blockIdx.x * 256;
  const int m0 = blockIdx.y * 128;

  // stage A K-half (128x32 = 8KB, 1 glds/thread)
  auto stA = [&](int kt1, int kh, int buf) {
    const int row = t >> 2, c16 = t & 3;
    const int kk  = kt1 * 64 + kh * 32 + ((c16 ^ ((row >> 1) & 3)) * 8);
    glds16(x + (size_t)(m0 + row) * EMB + kk, &sA[buf][kh][t * 8]);
  };
  // stage B K-half (256x32 = 16KB, 2 glds/thread)
  auto stB = [&](int kt1, int kh, int buf) {
#pragma unroll
    for (int i = 0; i < 2; ++i) {
      const int lin = i * 512 + t;
      const int row = lin >> 2, c16 = lin & 3;
      const int kk  = kt1 * 64 + kh * 32 + ((c16 ^ ((row >> 1) & 3)) * 8);
      glds16(wq + (size_t)(n0 + row) * EMB + kk, &sB[buf][kh][lin * 8]);
    }
  };
  auto rdA = [&](int buf, int kh, int mi) -> bf16x8 {
    const int r  = wm * 64 + mi * 16 + l15;
    const int cb = (quad ^ ((r >> 1) & 3)) * 16;
    return *(const bf16x8*)((const char*)&sA[buf][kh][0] + r * 64 + cb);
  };
  auto rdB = [&](int buf, int kh, int ni) -> bf16x8 {
    const int r  = wn * 64 + ni * 16 + l15;
    const int cb = (quad ^ ((r >> 1) & 3)) * 16;
    return *(const bf16x8*)((const char*)&sB[buf][kh][0] + r * 64 + cb);
  };

  f32x4 acc[4][4];
#pragma unroll
  for (int mi = 0; mi < 4; ++mi)
#pragma unroll
    for (int ni = 0; ni < 4; ++ni)
#pragma unroll
      for (int r = 0; r < 4; ++r) acc[mi][ni][r] = 0.f;

  // prologue: stage all 4 halves of kt=0; confirm Kh0; Kh1 stays in flight
  stA(0, 0, 0); stB(0, 0, 0); stA(0, 1, 0); stB(0, 1, 0);
  asm volatile("s_waitcnt vmcnt(3)" ::: "memory");
  __builtin_amdgcn_s_barrier();

  for (int kt = 0; kt < 32; ++kt) {
    const int b = kt & 1, nb = b ^ 1;
    const bool pre = (kt + 1 < 32);
    bf16x8 af[4], bq[4];

    // ---- P1: Kh0, ni 0-1 ----
    if (pre) stA(kt + 1, 0, nb);
#pragma unroll
    for (int mi = 0; mi < 4; ++mi) af[mi] = rdA(b, 0, mi);
    bq[0] = rdB(b, 0, 0); bq[1] = rdB(b, 0, 1);
    __builtin_amdgcn_s_setprio(1);
#pragma unroll
    for (int mi = 0; mi < 4; ++mi)
#pragma unroll
      for (int ni = 0; ni < 2; ++ni)
        acc[mi][ni] = __builtin_amdgcn_mfma_f32_16x16x32_bf16(af[mi], bq[ni], acc[mi][ni], 0, 0, 0);
    __builtin_amdgcn_s_setprio(0);
    asm volatile("" ::: "memory");
    __builtin_amdgcn_s_barrier();

    // ---- P2: Kh0, ni 2-3 ----
    if (pre) stB(kt + 1, 0, nb);
    bq[2] = rdB(b, 0, 2); bq[3] = rdB(b, 0, 3);
    __builtin_amdgcn_s_setprio(1);
#pragma unroll
    for (int mi = 0; mi < 4; ++mi)
#pragma unroll
      for (int ni = 2; ni < 4; ++ni)
        acc[mi][ni] = __builtin_amdgcn_mfma_f32_16x16x32_bf16(af[mi], bq[ni], acc[mi][ni], 0, 0, 0);
    __builtin_amdgcn_s_setprio(0);
    if (pre) asm volatile("s_waitcnt vmcnt(3)" ::: "memory");
    else     asm volatile("s_waitcnt vmcnt(0)" ::: "memory");
    __builtin_amdgcn_s_barrier();

    // ---- P3: Kh1, ni 0-1 ----
    if (pre) stA(kt + 1, 1, nb);
#pragma unroll
    for (int mi = 0; mi < 4; ++mi) af[mi] = rdA(b, 1, mi);
    bq[0] = rdB(b, 1, 0); bq[1] = rdB(b, 1, 1);
    __builtin_amdgcn_s_setprio(1);
#pragma unroll
    for (int mi = 0; mi < 4; ++mi)
#pragma unroll
      for (int ni = 0; ni < 2; ++ni)
        acc[mi][ni] = __builtin_amdgcn_mfma_f32_16x16x32_bf16(af[mi], bq[ni], acc[mi][ni], 0, 0, 0);
    __builtin_amdgcn_s_setprio(0);
    asm volatile("" ::: "memory");
    __builtin_amdgcn_s_barrier();

    // ---- P4: Kh1, ni 2-3 ----
    if (pre) stB(kt + 1, 1, nb);
    bq[2] = rdB(b, 1, 2); bq[3] = rdB(b, 1, 3);
    __builtin_amdgcn_s_setprio(1);
#pragma unroll
    for (int mi = 0; mi < 4; ++mi)
#pragma unroll
      for (int ni = 2; ni < 4; ++ni)
        acc[mi][ni] = __builtin_amdgcn_mfma_f32_16x16x32_bf16(af[mi], bq[ni], acc[mi][ni], 0, 0, 0);
    __builtin_amdgcn_s_setprio(0);
    if (pre) asm volatile("s_waitcnt vmcnt(3)" ::: "memory");
    else     asm volatile("s_waitcnt vmcnt(0)" ::: "memory");
    __builtin_amdgcn_s_barrier();
  }

  // ---- epilogue: bias + scatter (Q/K [b,h,s,d]; V transposed [b,h,d,s]) ----
  const int which = n0 >> 11;                 // 0=q,1=k,2=v (block-uniform)
  bf16* dst = (which == 0) ? q_ws : ((which == 1) ? k_ws : v_t);

#pragma unroll
  for (int mi = 0; mi < 4; ++mi) {
#pragma unroll
    for (int ni = 0; ni < 4; ++ni) {
      const int n_g = n0 + wn * 64 + ni * 16 + l15;
      const int h   = (n_g >> 7) & 15;
      const int d   = n_g & 127;
      const float bv = bias[n_g];
#pragma unroll
      for (int r = 0; r < 4; ++r) {
        const int m_g = m0 + wm * 64 + mi * 16 + quad * 4 + r;
        const int b_  = m_g >> 11;
        const int s   = m_g & 2047;
        const size_t idx = (which == 2)
            ? ((size_t)(b_ * NH + h) * HD + d) * S_LEN + s      // V: [b,h,d,s]
            : ((size_t)(b_ * NH + h) * S_LEN + s) * HD + d;     // Q/K: [b,h,s,d]
        dst[idx] = __float2bfloat16(acc[mi][ni][r] + bv);
      }
    }
  }
}

// ---------------------------------------------------------------------------
// Kernel 2: causal flash attention (unchanged — passed rounds 1-3).
// ---------------------------------------------------------------------------
__global__ __launch_bounds__(256, 1) void attn_k(
    const bf16* __restrict__ q_ws, const bf16* __restrict__ k_ws,
    const bf16* __restrict__ v_t, bf16* __restrict__ attn_out)
{
  __shared__ alignas(16) bf16 smK[2][8192];
  __shared__ alignas(16) bf16 smV[2][8192];
  __shared__ alignas(16) bf16 smP[4][32 * 72];

  const int t    = threadIdx.x;
  const int lane = t & 63, quad = lane >> 4, l15 = lane & 15;
  const int w    = t >> 6;
  const int bh   = blockIdx.x >> 3;
  const int pr   = blockIdx.x & 7;
  const size_t hb = (size_t)bh * (S_LEN * HD);
  const int col8 = (t & 3) * 8;
  bf16* myP = smP[w];
  const float C = 0.12751745f;   // (1/sqrt(128)) * log2(e)

  auto stageK = [&](int kv0, bf16* dst) {
#pragma unroll
    for (int i = 0; i < 4; i++) {
      const int lin = i * 256 + t;
      const int c   = lin >> 8;
      const int row = (lin >> 2) & 63;
      glds16(k_ws + hb + (size_t)(kv0 + row) * HD + c * 32 + col8, dst + (size_t)lin * 8);
    }
  };
  auto stageV = [&](int kv0, bf16* dst) {
#pragma unroll
    for (int i = 0; i < 4; i++) {
      const int lin = i * 256 + t;
      const int c   = lin >> 9;
      const int row = (lin >> 2) & 127;
      glds16(v_t + hb + (size_t)row * S_LEN + kv0 + c * 32 + col8, dst + (size_t)lin * 8);
    }
  };

  for (int ph = 0; ph < 2; ++ph) {
    const int qt     = ph ? pr : (15 - pr);
    const int qbase  = qt * 128;
    const int ntiles = 2 * qt + 2;
    const int wrow0  = qbase + w * 32;
    const int wrow_hi = wrow0 + 31;

    bf16x8 qf[2][4];
#pragma unroll
    for (int mi = 0; mi < 2; ++mi)
#pragma unroll
      for (int ks = 0; ks < 4; ++ks)
        qf[mi][ks] = *(const bf16x8*)(q_ws + hb + (size_t)(wrow0 + mi * 16 + l15) * HD + ks * 32 + quad * 8);

    f32x4 o_acc[2][8];
    float m_st[2][4], l_st[2][4];
#pragma unroll
    for (int mi = 0; mi < 2; ++mi) {
#pragma unroll
      for (int dt = 0; dt < 8; ++dt)
#pragma unroll
        for (int r = 0; r < 4; ++r) o_acc[mi][dt][r] = 0.f;
#pragma unroll
      for (int r = 0; r < 4; ++r) { m_st[mi][r] = -1e30f; l_st[mi][r] = 0.f; }
    }

    stageK(0, smK[0]);
    stageV(0, smV[0]);

    for (int tile = 0; tile < ntiles; ++tile) {
      const int cur = tile & 1;
      if (tile + 1 < ntiles) {
        const int kv1 = (tile + 1) * 64;
        stageK(kv1, smK[cur ^ 1]);
        stageV(kv1, smV[cur ^ 1]);
        asm volatile("s_waitcnt vmcnt(8)" ::: "memory");
      } else {
        asm volatile("s_waitcnt vmcnt(0)" ::: "memory");
      }
      __builtin_amdgcn_s_barrier();

      const int kv0 = tile * 64;
      if (kv0 <= wrow_hi) {
        f32x4 sc[2][4];
#pragma unroll
        for (int mi = 0; mi < 2; mi++)
#pragma unroll
          for (int ni = 0; ni < 4; ni++)
#pragma unroll
            for (int r = 0; r < 4; r++) sc[mi][ni][r] = 0.f;
        const bf16* kb = smK[cur];
#pragma unroll
        for (int ks = 0; ks < 4; ++ks) {
          bf16x8 kf[4];
#pragma unroll
          for (int ni = 0; ni < 4; ++ni)
            kf[ni] = *(const bf16x8*)(kb + (ks * 64 + ni * 16 + l15) * 32 + quad * 8);
#pragma unroll
          for (int mi = 0; mi < 2; ++mi)
#pragma unroll
            for (int ni = 0; ni < 4; ++ni)
              sc[mi][ni] = __builtin_amdgcn_mfma_f32_16x16x32_bf16(qf[mi][ks], kf[ni], sc[mi][ni], 0, 0, 0);
        }

#pragma unroll
        for (int mi = 0; mi < 2; ++mi) {
          const int mrow0 = wrow0 + mi * 16;
          const bool needmask = (kv0 + 63 > mrow0);
#pragma unroll
          for (int r = 0; r < 4; ++r) {
            const int qg = mrow0 + quad * 4 + r;
            float xs[4];
            float vmax = -1e30f;
            if (needmask) {
#pragma unroll
              for (int ni = 0; ni < 4; ++ni) {
                const int kg = kv0 + ni * 16 + l15;
                float xv = sc[mi][ni][r] * C;
                xv = (kg > qg) ? -1e30f : xv;
                xs[ni] = xv;
                vmax = fmaxf(vmax, xv);
              }
            } else {
#pragma unroll
              for (int ni = 0; ni < 4; ++ni) {
                const float xv = sc[mi][ni][r] * C;
                xs[ni] = xv;
                vmax = fmaxf(vmax, xv);
              }
            }
            float m_old = m_st[mi][r];
            if (!__all(vmax <= m_old + 8.f)) {
#pragma unroll
              for (int off = 1; off < 16; off <<= 1)
                vmax = fmaxf(vmax, __shfl_xor(vmax, off, 64));
              const float mnew  = fmaxf(m_old, vmax);
              const float alpha = __builtin_amdgcn_exp2f(m_old - mnew);
              l_st[mi][r] *= alpha;
#pragma unroll
              for (int dt = 0; dt < 8; ++dt) o_acc[mi][dt][r] *= alpha;
              m_st[mi][r] = mnew;
              m_old = mnew;
            }
            float ps = 0.f;
#pragma unroll
            for (int ni = 0; ni < 4; ++ni) {
              const float p = __builtin_amdgcn_exp2f(xs[ni] - m_old);
              ps += p;
              myP[(mi * 16 + quad * 4 + r) * 72 + ni * 16 + l15] = __float2bfloat16(p);
            }
            l_st[mi][r] += ps;
          }
        }

        const bf16* vb = smV[cur];
#pragma unroll
        for (int ks2 = 0; ks2 < 2; ++ks2) {
          bf16x8 pa[2];
#pragma unroll
          for (int mi = 0; mi < 2; ++mi)
            pa[mi] = *(const bf16x8*)(myP + (mi * 16 + l15) * 72 + ks2 * 32 + quad * 8);
#pragma unroll
          for (int dt = 0; dt < 8; ++dt) {
            const bf16x8 vf = *(const bf16x8*)(vb + (ks2 * 128 + dt * 16 + l15) * 32 + quad * 8);
#pragma unroll
            for (int mi = 0; mi < 2; ++mi)
              o_acc[mi][dt] = __builtin_amdgcn_mfma_f32_16x16x32_bf16(pa[mi], vf, o_acc[mi][dt], 0, 0, 0);
          }
        }
      }
      __builtin_amdgcn_s_barrier();
    }

#pragma unroll
    for (int mi = 0; mi < 2; ++mi) {
#pragma unroll
      for (int r = 0; r < 4; ++r) {
        float l = l_st[mi][r];
#pragma unroll
        for (int off = 1; off < 16; off <<= 1) l += __shfl_xor(l, off, 64);
        const float rl = 1.f / l;
        const int sg = qbase + w * 32 + mi * 16 + quad * 4 + r;
        const size_t rowoff = hb + (size_t)sg * HD;
#pragma unroll
        for (int dt = 0; dt < 8; ++dt)
          attn_out[rowoff + dt * 16 + l15] = __float2bfloat16(o_acc[mi][dt][r] * rl);
      }
    }
  }
}

// ---------------------------------------------------------------------------
// Kernel 3: out = attn @ w_out^T + b_out, attn stored [b,h,s,d]
// (logical A[m = b*2048+s][k = h*128+d]). OUTPUT FLOAT32. Grid (8,32)=256.
// Same phased structure as gemm_qkv_k.
// ---------------------------------------------------------------------------
__global__ __launch_bounds__(512, 2) void gemm_out_k(
    const bf16* __restrict__ attn, const bf16* __restrict__ wo,
    const float* __restrict__ bias, float* __restrict__ out)
{
  __shared__ alignas(16) bf16 sA[2][2][128 * 32];
  __shared__ alignas(16) bf16 sB[2][2][256 * 32];

  const int t    = threadIdx.x;
  const int lane = t & 63, quad = lane >> 4, l15 = lane & 15;
  const int w    = t >> 6, wm = w >> 2, wn = w & 3;

  const int n0 = blockIdx.x * 256;
  const int m0 = blockIdx.y * 128;

  auto stA = [&](int kt1, int kh, int buf) {
    const int row = t >> 2, c16 = t & 3;
    const int kk  = kt1 * 64 + kh * 32 + ((c16 ^ ((row >> 1) & 3)) * 8);
    const int h   = kk >> 7;
    const int dc  = kk & 127;
    const int m   = m0 + row;
    const int b_  = m >> 11;
    const int s   = m & 2047;
    glds16(attn + ((size_t)(b_ * NH + h) * S_LEN + s) * HD + dc, &sA[buf][kh][t * 8]);
  };
  auto stB = [&](int kt1, int kh, int buf) {
#pragma unroll
    for (int i = 0; i < 2; ++i) {
      const int lin = i * 512 + t;
      const int row = lin >> 2, c16 = lin & 3;
      const int kk  = kt1 * 64 + kh * 32 + ((c16 ^ ((row >> 1) & 3)) * 8);
      glds16(wo + (size_t)(n0 + row) * EMB + kk, &sB[buf][kh][lin * 8]);
    }
  };
  auto rdA = [&](int buf, int kh, int mi) -> bf16x8 {
    const int r  = wm * 64 + mi * 16 + l15;
    const int cb = (quad ^ ((r >> 1) & 3)) * 16;
    return *(const bf16x8*)((const char*)&sA[buf][kh][0] + r * 64 + cb);
  };
  auto rdB = [&](int buf, int kh, int ni) -> bf16x8 {
    const int r  = wn * 64 + ni * 16 + l15;
    const int cb = (quad ^ ((r >> 1) & 3)) * 16;
    return *(const bf16x8*)((const char*)&sB[buf][kh][0] + r * 64 + cb);
  };

  f32x4 acc[4][4];
#pragma unroll
  for (int mi = 0; mi < 4; ++mi)
#pragma unroll
    for (int ni = 0; ni < 4; ++ni)
#pragma unroll
      for (int r = 0; r < 4; ++r) acc[mi][ni][r] = 0.f;

  stA(0, 0, 0); stB(0, 0, 0); stA(0, 1, 0); stB(0, 1, 0);
  asm volatile("s_waitcnt vmcnt(3)" ::: "memory");
  __builtin_amdgcn_s_barrier();

  for (int kt = 0; kt < 32; ++kt) {
    const int b = kt & 1, nb = b ^ 1;
    const bool pre = (kt + 1 < 32);
    bf16x8 af[4], bq[4];

    // ---- P1 ----
    if (pre) stA(kt + 1, 0, nb);
#pragma unroll
    for (int mi = 0; mi < 4; ++mi) af[mi] = rdA(b, 0, mi);
    bq[0] = rdB(b, 0, 0); bq[1] = rdB(b, 0, 1);
    __builtin_amdgcn_s_setprio(1);
#pragma unroll
    for (int mi = 0; mi < 4; ++mi)
#pragma unroll
      for (int ni = 0; ni < 2; ++ni)
        acc[mi][ni] = __builtin_amdgcn_mfma_f32_16x16x32_bf16(af[mi], bq[ni], acc[mi][ni], 0, 0, 0);
    __builtin_amdgcn_s_setprio(0);
    asm volatile("" ::: "memory");
    __builtin_amdgcn_s_barrier();

    // ---- P2 ----
    if (pre) stB(kt + 1, 0, nb);
    bq[2] = rdB(b, 0, 2); bq[3] = rdB(b, 0, 3);
    __builtin_amdgcn_s_setprio(1);
#pragma unroll
    for (int mi = 0; mi < 4; ++mi)
#pragma unroll
      for (int ni = 2; ni < 4; ++ni)
        acc[mi][ni] = __builtin_amdgcn_mfma_f32_16x16x32_bf16(af[mi], bq[ni], acc[mi][ni], 0, 0, 0);
    __builtin_amdgcn_s_setprio(0);
    if (pre) asm volatile("s_waitcnt vmcnt(3)" ::: "memory");
    else     asm volatile("s_waitcnt vmcnt(0)" ::: "memory");
    __builtin_amdgcn_s_barrier();

    // ---- P3 ----
    if (pre) stA(kt + 1, 1, nb);
#pragma unroll
    for (int mi = 0; mi < 4; ++mi) af[mi] = rdA(b, 1, mi);
    bq[0] = rdB(b, 1, 0); bq[1] = rdB(b, 1, 1);
    __builtin_amdgcn_s_setprio(1);
#pragma unroll
    for (int mi = 0; mi < 4; ++mi)
#pragma unroll
      for (int ni = 0; ni < 2; ++ni)
        acc[mi][ni] = __builtin_amdgcn_mfma_f32_16x16x32_bf16(af[mi], bq[ni], acc[mi][ni], 0, 0, 0);
    __builtin_amdgcn_s_setprio(0);
    asm volatile("" ::: "memory");
    __builtin_amdgcn_s_barrier();

    // ---- P4 ----
    if (pre) stB(kt + 1, 1, nb);
    bq[2] = rdB(b, 1, 2); bq[3] = rdB(b, 1, 3);
    __builtin_amdgcn_s_setprio(1);
#pragma unroll
    for (int mi = 0; mi < 4; ++mi)
#pragma unroll
      for (int ni = 2; ni < 4; ++ni)
        acc[mi][ni] = __builtin_amdgcn_mfma_f32_16x16x32_bf16(af[mi], bq[ni], acc[mi][ni], 0, 0, 0);
    __builtin_amdgcn_s_setprio(0);
    if (pre) asm volatile("s_waitcnt vmcnt(3)" ::: "memory");
    else     asm volatile("s_waitcnt vmcnt(0)" ::: "memory");
    __builtin_amdgcn_s_barrier();
  }

#pragma unroll
  for (int mi = 0; mi < 4; ++mi) {
#pragma unroll
    for (int ni = 0; ni < 4; ++ni) {
      const int n_g = n0 + wn * 64 + ni * 16 + l15;
      const float bv = bias[n_g];
#pragma unroll
      for (int r = 0; r < 4; ++r) {
        const int m_g = m0 + wm * 64 + mi * 16 + quad * 4 + r;
        out[(size_t)m_g * EMB + n_g] = acc[mi][ni][r] + bv;   // f32 store
      }
    }
  }
}

// ---------------------------------------------------------------------------
// Workspace layout (96 MiB):
//   [ 0,16)  MiB: xb  bf16 (x converted) -> attn output [b,h,s,d] after QKV
//   [16,40)  MiB: wqb bf16 (w_qkv converted)
//   [40,48)  MiB: wob bf16 (w_out converted)
//   [48,64)  MiB: q [b,h,s,d]
//   [64,80)  MiB: k [b,h,s,d]
//   [80,96)  MiB: v_t [b,h,d,s]
// ---------------------------------------------------------------------------
extern "C" void kernel_launch(void* const* d_in, const int* in_sizes, int n_in,
                              void* d_out, int out_size, void* d_ws, size_t ws_size,
                              hipStream_t stream)
{
  const float* x_f     = (const float*)d_in[0];
  // d_in[1] = attn_mask (causal triu) — known analytically, ignored.
  const float* w_qkv_f = (const float*)d_in[2];
  const float* b_qkv   = (const float*)d_in[3];
  const float* w_out_f = (const float*)d_in[4];
  const float* b_out   = (const float*)d_in[5];
  float* out = (float*)d_out;   // reference output dtype is float32

  char* ws = (char*)d_ws;
  const size_t MB = 1024 * 1024;
  bf16* xb   = (bf16*)(ws);
  bf16* wqb  = (bf16*)(ws + 16 * MB);
  bf16* wob  = (bf16*)(ws + 40 * MB);
  bf16* q_ws = (bf16*)(ws + 48 * MB);
  bf16* k_ws = (bf16*)(ws + 64 * MB);
  bf16* v_t  = (bf16*)(ws + 80 * MB);
  bf16* attn = xb;   // xb dead after gemm_qkv_k; distinct from q_ws (no alias)

  cvt_f32_bf16_k<<<dim3(8192), 256, 0, stream>>>(x_f, xb);
  cvt_f32_bf16_k<<<dim3(12288), 256, 0, stream>>>(w_qkv_f, wqb);
  cvt_f32_bf16_k<<<dim3(4096), 256, 0, stream>>>(w_out_f, wob);

  gemm_qkv_k<<<dim3(24, 32), 512, 0, stream>>>(xb, wqb, b_qkv, q_ws, k_ws, v_t);
  attn_k<<<dim3(256), 256, 0, stream>>>(q_ws, k_ws, v_t, attn);
  gemm_out_k<<<dim3(8, 32), 512, 0, stream>>>(attn, wob, b_out, out);
}

// Round 5
// 441.970 us; speedup vs baseline: 1.1641x; 1.1641x over previous
//
#include <hip/hip_runtime.h>
#include <hip/hip_bf16.h>
#include <stdint.h>

typedef __hip_bfloat16 bf16;
typedef __bf16 bf16x8 __attribute__((ext_vector_type(8)));
typedef float f32x4 __attribute__((ext_vector_type(4)));

#define S_LEN 2048
#define EMB   2048
#define NH    16
#define HD    128

// async global->LDS, 16B per lane. LDS dest must be wave-uniform base + lane*16.
__device__ __forceinline__ void glds16(const void* g, void* l) {
  __builtin_amdgcn_global_load_lds(
      (__attribute__((address_space(1))) void*)g,
      (__attribute__((address_space(3))) void*)l,
      16, 0, 0);
}

// ---------------------------------------------------------------------------
// Kernel 0: fused f32 -> bf16 conversion of x, w_qkv, w_out (one launch).
// Ranges: [0,8192) x ; [8192,20480) w_qkv ; [20480,24576) w_out.
// ---------------------------------------------------------------------------
__global__ __launch_bounds__(256) void cvt3_k(
    const float* __restrict__ xa, bf16* __restrict__ xo,
    const float* __restrict__ wa, bf16* __restrict__ wo1,
    const float* __restrict__ oa, bf16* __restrict__ oo)
{
  const int bid = blockIdx.x;
  const float* src; bf16* dst; int i;
  if (bid < 8192)       { src = xa; dst = xo;  i = bid * 256 + threadIdx.x; }
  else if (bid < 20480) { src = wa; dst = wo1; i = (bid - 8192) * 256 + threadIdx.x; }
  else                  { src = oa; dst = oo;  i = (bid - 20480) * 256 + threadIdx.x; }
  const float4 v = ((const float4*)src)[i];
  bf16 tmp[4];
  tmp[0] = __float2bfloat16(v.x);
  tmp[1] = __float2bfloat16(v.y);
  tmp[2] = __float2bfloat16(v.z);
  tmp[3] = __float2bfloat16(v.w);
  ((uint2*)dst)[i] = *(const uint2*)tmp;
}

// ---------------------------------------------------------------------------
// Kernel 1: qkv = x @ w_qkv^T + b_qkv  (R1-measured version, 153.6 us).
// Q,K scattered into [b,h,s,d]; V written TRANSPOSED into v_t [b,h,d,s].
// ---------------------------------------------------------------------------
__global__ __launch_bounds__(256) void gemm_qkv_k(
    const bf16* __restrict__ x, const bf16* __restrict__ w,
    const float* __restrict__ bias,
    bf16* __restrict__ q_ws, bf16* __restrict__ k_ws, bf16* __restrict__ v_t)
{
  __shared__ alignas(16) bf16 sA[128 * 32];
  __shared__ alignas(16) bf16 sW[128 * 32];
  const int n0 = blockIdx.x * 128;
  const int m0 = blockIdx.y * 128;

  const int t    = threadIdx.x;
  const int lane = t & 63, quad = lane >> 4, l15 = lane & 15;
  const int wave = t >> 6;
  const int wm0  = (wave >> 1) * 64, wn0 = (wave & 1) * 64;
  const int col8 = (t & 3) * 8;

  f32x4 acc[4][4];
#pragma unroll
  for (int mi = 0; mi < 4; mi++)
#pragma unroll
    for (int ni = 0; ni < 4; ni++)
#pragma unroll
      for (int r = 0; r < 4; r++) acc[mi][ni][r] = 0.f;

  for (int k0 = 0; k0 < EMB; k0 += 32) {
#pragma unroll
    for (int i = 0; i < 2; i++) {
      const int lin = i * 256 + t;       // 0..511
      const int row = lin >> 2;          // 0..127
      glds16(x + (size_t)(m0 + row) * EMB + k0 + col8, sA + (size_t)lin * 8);
      glds16(w + (size_t)(n0 + row) * EMB + k0 + col8, sW + (size_t)lin * 8);
    }
    __syncthreads();
    bf16x8 af[4], wf[4];
#pragma unroll
    for (int mi = 0; mi < 4; mi++)
      af[mi] = *(const bf16x8*)(sA + (wm0 + mi * 16 + l15) * 32 + quad * 8);
#pragma unroll
    for (int ni = 0; ni < 4; ni++)
      wf[ni] = *(const bf16x8*)(sW + (wn0 + ni * 16 + l15) * 32 + quad * 8);
#pragma unroll
    for (int mi = 0; mi < 4; mi++)
#pragma unroll
      for (int ni = 0; ni < 4; ni++)
        acc[mi][ni] = __builtin_amdgcn_mfma_f32_16x16x32_bf16(af[mi], wf[ni], acc[mi][ni], 0, 0, 0);
    __syncthreads();
  }

  const int which = n0 >> 11;                 // 0=q,1=k,2=v (whole block same)
  bf16* dst = (which == 0) ? q_ws : ((which == 1) ? k_ws : v_t);

#pragma unroll
  for (int mi = 0; mi < 4; mi++) {
#pragma unroll
    for (int ni = 0; ni < 4; ni++) {
      const int n_g = n0 + wn0 + ni * 16 + l15;
      const int h   = (n_g >> 7) & 15;
      const int d   = n_g & 127;
      const float bv = bias[n_g];
#pragma unroll
      for (int r = 0; r < 4; r++) {
        const int m_g = m0 + wm0 + mi * 16 + quad * 4 + r;
        const int b   = m_g >> 11;
        const int s   = m_g & 2047;
        const size_t idx = (which == 2)
            ? ((size_t)(b * NH + h) * HD + d) * S_LEN + s      // V: [b,h,d,s]
            : ((size_t)(b * NH + h) * S_LEN + s) * HD + d;     // Q/K: [b,h,s,d]
        dst[idx] = __float2bfloat16(acc[mi][ni][r] + bv);
      }
    }
  }
}

// ---------------------------------------------------------------------------
// Kernel 2: causal flash attention. R1 structure (balanced pairing, K/V
// double-buffer, counted vmcnt, softmax diet) + this round:
//   * K/V LDS XOR-swizzle  slot ^= (row>>1)&3  on the 64B rows
//     (inverse-swizzled GLOBAL source, linear glds dest, swizzled read).
//     Kills the 8-way ds_read_b128 bank conflict (16 lanes -> 2/bank = free).
//   * s_setprio(1) around QK^T and PV MFMA clusters (m191: +4-7% attn).
// ---------------------------------------------------------------------------
__global__ __launch_bounds__(256, 1) void attn_k(
    const bf16* __restrict__ q_ws, const bf16* __restrict__ k_ws,
    const bf16* __restrict__ v_t, bf16* __restrict__ attn_out)
{
  __shared__ alignas(16) bf16 smK[2][8192];
  __shared__ alignas(16) bf16 smV[2][8192];
  __shared__ alignas(16) bf16 smP[4][32 * 72];

  const int t    = threadIdx.x;
  const int lane = t & 63, quad = lane >> 4, l15 = lane & 15;
  const int w    = t >> 6;
  const int bh   = blockIdx.x >> 3;
  const int pr   = blockIdx.x & 7;
  const size_t hb = (size_t)bh * (S_LEN * HD);
  bf16* myP = smP[w];
  const float C = 0.12751745f;   // (1/sqrt(128)) * log2(e)
  // swizzled 16B-slot for LDS reads of K/V (row = **16 + l15 -> (l15>>1)&3)
  const int sw = quad ^ ((l15 >> 1) & 3);

  auto stageK = [&](int kv0, bf16* dst) {
#pragma unroll
    for (int i = 0; i < 4; i++) {
      const int lin = i * 256 + t;
      const int c   = lin >> 8;              // k-chunk 0..3
      const int row = (lin >> 2) & 63;
      const int sl  = (t & 3) ^ ((row >> 1) & 3);   // inverse-swizzled source
      glds16(k_ws + hb + (size_t)(kv0 + row) * HD + c * 32 + sl * 8,
             dst + (size_t)lin * 8);
    }
  };
  auto stageV = [&](int kv0, bf16* dst) {
#pragma unroll
    for (int i = 0; i < 4; i++) {
      const int lin = i * 256 + t;
      const int c   = lin >> 9;              // s-chunk 0..1
      const int row = (lin >> 2) & 127;      // d index
      const int sl  = (t & 3) ^ ((row >> 1) & 3);
      glds16(v_t + hb + (size_t)row * S_LEN + kv0 + c * 32 + sl * 8,
             dst + (size_t)lin * 8);
    }
  };

  for (int ph = 0; ph < 2; ++ph) {
    const int qt     = ph ? pr : (15 - pr);   // heavy tile first
    const int qbase  = qt * 128;
    const int ntiles = 2 * qt + 2;
    const int wrow0  = qbase + w * 32;
    const int wrow_hi = wrow0 + 31;

    // Q fragments straight from global (registers; no LDS staging)
    bf16x8 qf[2][4];
#pragma unroll
    for (int mi = 0; mi < 2; ++mi)
#pragma unroll
      for (int ks = 0; ks < 4; ++ks)
        qf[mi][ks] = *(const bf16x8*)(q_ws + hb + (size_t)(wrow0 + mi * 16 + l15) * HD + ks * 32 + quad * 8);

    f32x4 o_acc[2][8];
    float m_st[2][4], l_st[2][4];
#pragma unroll
    for (int mi = 0; mi < 2; ++mi) {
#pragma unroll
      for (int dt = 0; dt < 8; ++dt)
#pragma unroll
        for (int r = 0; r < 4; ++r) o_acc[mi][dt][r] = 0.f;
#pragma unroll
      for (int r = 0; r < 4; ++r) { m_st[mi][r] = -1e30f; l_st[mi][r] = 0.f; }
    }

    stageK(0, smK[0]);
    stageV(0, smV[0]);

    for (int tile = 0; tile < ntiles; ++tile) {
      const int cur = tile & 1;
      if (tile + 1 < ntiles) {
        const int kv1 = (tile + 1) * 64;
        stageK(kv1, smK[cur ^ 1]);
        stageV(kv1, smV[cur ^ 1]);
        asm volatile("s_waitcnt vmcnt(8)" ::: "memory");   // keep prefetch in flight
      } else {
        asm volatile("s_waitcnt vmcnt(0)" ::: "memory");
      }
      __builtin_amdgcn_s_barrier();

      const int kv0 = tile * 64;
      if (kv0 <= wrow_hi) {
        // ---- QK^T ----
        f32x4 sc[2][4];
#pragma unroll
        for (int mi = 0; mi < 2; mi++)
#pragma unroll
          for (int ni = 0; ni < 4; ni++)
#pragma unroll
            for (int r = 0; r < 4; r++) sc[mi][ni][r] = 0.f;
        const bf16* kb = smK[cur];
        __builtin_amdgcn_s_setprio(1);
#pragma unroll
        for (int ks = 0; ks < 4; ++ks) {
          bf16x8 kf[4];
#pragma unroll
          for (int ni = 0; ni < 4; ++ni)
            kf[ni] = *(const bf16x8*)(kb + (ks * 64 + ni * 16 + l15) * 32 + sw * 8);
#pragma unroll
          for (int mi = 0; mi < 2; ++mi)
#pragma unroll
            for (int ni = 0; ni < 4; ++ni)
              sc[mi][ni] = __builtin_amdgcn_mfma_f32_16x16x32_bf16(qf[mi][ks], kf[ni], sc[mi][ni], 0, 0, 0);
        }
        __builtin_amdgcn_s_setprio(0);

        // ---- online softmax (exp2 domain, defer-max, per-lane l) ----
#pragma unroll
        for (int mi = 0; mi < 2; ++mi) {
          const int mrow0 = wrow0 + mi * 16;
          const bool needmask = (kv0 + 63 > mrow0);   // wave-uniform
#pragma unroll
          for (int r = 0; r < 4; ++r) {
            const int qg = mrow0 + quad * 4 + r;
            float xs[4];
            float vmax = -1e30f;
            if (needmask) {
#pragma unroll
              for (int ni = 0; ni < 4; ++ni) {
                const int kg = kv0 + ni * 16 + l15;
                float xv = sc[mi][ni][r] * C;
                xv = (kg > qg) ? -1e30f : xv;
                xs[ni] = xv;
                vmax = fmaxf(vmax, xv);
              }
            } else {
#pragma unroll
              for (int ni = 0; ni < 4; ++ni) {
                const float xv = sc[mi][ni][r] * C;
                xs[ni] = xv;
                vmax = fmaxf(vmax, xv);
              }
            }
            float m_old = m_st[mi][r];
            if (!__all(vmax <= m_old + 8.f)) {        // rare after tile 0
#pragma unroll
              for (int off = 1; off < 16; off <<= 1)
                vmax = fmaxf(vmax, __shfl_xor(vmax, off, 64));
              const float mnew  = fmaxf(m_old, vmax);
              const float alpha = __builtin_amdgcn_exp2f(m_old - mnew);
              l_st[mi][r] *= alpha;
#pragma unroll
              for (int dt = 0; dt < 8; ++dt) o_acc[mi][dt][r] *= alpha;
              m_st[mi][r] = mnew;
              m_old = mnew;
            }
            float ps = 0.f;
#pragma unroll
            for (int ni = 0; ni < 4; ++ni) {
              const float p = __builtin_amdgcn_exp2f(xs[ni] - m_old);
              ps += p;
              myP[(mi * 16 + quad * 4 + r) * 72 + ni * 16 + l15] = __float2bfloat16(p);
            }
            l_st[mi][r] += ps;   // per-lane partial; reduced once in epilogue
          }
        }

        // ---- P @ V (per-wave P, no barrier needed) ----
        const bf16* vb = smV[cur];
        __builtin_amdgcn_s_setprio(1);
#pragma unroll
        for (int ks2 = 0; ks2 < 2; ++ks2) {
          bf16x8 pa[2];
#pragma unroll
          for (int mi = 0; mi < 2; ++mi)
            pa[mi] = *(const bf16x8*)(myP + (mi * 16 + l15) * 72 + ks2 * 32 + quad * 8);
#pragma unroll
          for (int dt = 0; dt < 8; ++dt) {
            const bf16x8 vf = *(const bf16x8*)(vb + (ks2 * 128 + dt * 16 + l15) * 32 + sw * 8);
#pragma unroll
            for (int mi = 0; mi < 2; ++mi)
              o_acc[mi][dt] = __builtin_amdgcn_mfma_f32_16x16x32_bf16(pa[mi], vf, o_acc[mi][dt], 0, 0, 0);
          }
        }
        __builtin_amdgcn_s_setprio(0);
      }
      __builtin_amdgcn_s_barrier();   // all reads of buf[cur] done before reuse
    }

    // ---- epilogue: reduce l across the 16-lane row groups, write O/l ----
#pragma unroll
    for (int mi = 0; mi < 2; ++mi) {
#pragma unroll
      for (int r = 0; r < 4; ++r) {
        float l = l_st[mi][r];
#pragma unroll
        for (int off = 1; off < 16; off <<= 1) l += __shfl_xor(l, off, 64);
        const float rl = 1.f / l;
        const int sg = qbase + w * 32 + mi * 16 + quad * 4 + r;
        const size_t rowoff = hb + (size_t)sg * HD;
#pragma unroll
        for (int dt = 0; dt < 8; ++dt)
          attn_out[rowoff + dt * 16 + l15] = __float2bfloat16(o_acc[mi][dt][r] * rl);
      }
    }
  }
}

// ---------------------------------------------------------------------------
// Kernel 3: out = attn @ w_out^T + b_out  (R1-measured version).
// attn stored [b,h,s,d] (logical A[m=b*2048+s][k=h*128+d]). OUTPUT FLOAT32.
// ---------------------------------------------------------------------------
__global__ __launch_bounds__(256) void gemm_out_k(
    const bf16* __restrict__ attn, const bf16* __restrict__ w,
    const float* __restrict__ bias, float* __restrict__ out)
{
  __shared__ alignas(16) bf16 sA[128 * 32];
  __shared__ alignas(16) bf16 sW[128 * 32];
  const int n0 = blockIdx.x * 128;
  const int m0 = blockIdx.y * 128;

  const int t    = threadIdx.x;
  const int lane = t & 63, quad = lane >> 4, l15 = lane & 15;
  const int wave = t >> 6;
  const int wm0  = (wave >> 1) * 64, wn0 = (wave & 1) * 64;
  const int col8 = (t & 3) * 8;

  f32x4 acc[4][4];
#pragma unroll
  for (int mi = 0; mi < 4; mi++)
#pragma unroll
    for (int ni = 0; ni < 4; ni++)
#pragma unroll
      for (int r = 0; r < 4; r++) acc[mi][ni][r] = 0.f;

  for (int k0 = 0; k0 < EMB; k0 += 32) {
    const int kk = k0 + col8;
    const int h  = kk >> 7;          // head (constant across the 8-elt chunk)
    const int dc = kk & 127;
#pragma unroll
    for (int i = 0; i < 2; i++) {
      const int lin = i * 256 + t;       // 0..511
      const int row = lin >> 2;          // 0..127
      const int m   = m0 + row;
      const int b   = m >> 11;
      const int s   = m & 2047;
      glds16(attn + ((size_t)(b * NH + h) * S_LEN + s) * HD + dc, sA + (size_t)lin * 8);
      glds16(w + (size_t)(n0 + row) * EMB + k0 + col8, sW + (size_t)lin * 8);
    }
    __syncthreads();
    bf16x8 af[4], wf[4];
#pragma unroll
    for (int mi = 0; mi < 4; mi++)
      af[mi] = *(const bf16x8*)(sA + (wm0 + mi * 16 + l15) * 32 + quad * 8);
#pragma unroll
    for (int ni = 0; ni < 4; ni++)
      wf[ni] = *(const bf16x8*)(sW + (wn0 + ni * 16 + l15) * 32 + quad * 8);
#pragma unroll
    for (int mi = 0; mi < 4; mi++)
#pragma unroll
      for (int ni = 0; ni < 4; ni++)
        acc[mi][ni] = __builtin_amdgcn_mfma_f32_16x16x32_bf16(af[mi], wf[ni], acc[mi][ni], 0, 0, 0);
    __syncthreads();
  }

#pragma unroll
  for (int mi = 0; mi < 4; mi++) {
#pragma unroll
    for (int ni = 0; ni < 4; ni++) {
      const int n_g = n0 + wn0 + ni * 16 + l15;
      const float bv = bias[n_g];
#pragma unroll
      for (int r = 0; r < 4; r++) {
        const int m_g = m0 + wm0 + mi * 16 + quad * 4 + r;
        out[(size_t)m_g * EMB + n_g] = acc[mi][ni][r] + bv;   // f32 store
      }
    }
  }
}

// ---------------------------------------------------------------------------
// Workspace layout (96 MiB):
//   [ 0,16)  MiB: xb  bf16 (x converted) -> attn output [b,h,s,d] after QKV
//   [16,40)  MiB: wqb bf16 (w_qkv converted)
//   [40,48)  MiB: wob bf16 (w_out converted)
//   [48,64)  MiB: q [b,h,s,d]
//   [64,80)  MiB: k [b,h,s,d]
//   [80,96)  MiB: v_t [b,h,d,s] (written directly transposed by gemm_qkv_k)
// ---------------------------------------------------------------------------
extern "C" void kernel_launch(void* const* d_in, const int* in_sizes, int n_in,
                              void* d_out, int out_size, void* d_ws, size_t ws_size,
                              hipStream_t stream)
{
  const float* x_f     = (const float*)d_in[0];
  // d_in[1] = attn_mask (causal triu) — known analytically, ignored.
  const float* w_qkv_f = (const float*)d_in[2];
  const float* b_qkv   = (const float*)d_in[3];
  const float* w_out_f = (const float*)d_in[4];
  const float* b_out   = (const float*)d_in[5];
  float* out = (float*)d_out;   // reference output dtype is float32

  char* ws = (char*)d_ws;
  const size_t MB = 1024 * 1024;
  bf16* xb   = (bf16*)(ws);
  bf16* wqb  = (bf16*)(ws + 16 * MB);
  bf16* wob  = (bf16*)(ws + 40 * MB);
  bf16* q_ws = (bf16*)(ws + 48 * MB);
  bf16* k_ws = (bf16*)(ws + 64 * MB);
  bf16* v_t  = (bf16*)(ws + 80 * MB);
  bf16* attn = xb;   // xb dead after gemm_qkv_k; distinct from q_ws (no alias)

  cvt3_k<<<dim3(24576), 256, 0, stream>>>(x_f, xb, w_qkv_f, wqb, w_out_f, wob);

  gemm_qkv_k<<<dim3(48, 32), 256, 0, stream>>>(xb, wqb, b_qkv, q_ws, k_ws, v_t);
  attn_k<<<dim3(256), 256, 0, stream>>>(q_ws, k_ws, v_t, attn);
  gemm_out_k<<<dim3(16, 32), 256, 0, stream>>>(attn, wob, b_out, out);
}